// Round 4
// baseline (6942.349 us; speedup 1.0000x reference)
//
#include <hip/hip_runtime.h>
#include <math.h>

#define Bn   64
#define Sn   512
#define EMBn 128
#define HIDn 256
#define NG   1024   // 4*HID
#define NK   384    // 256 (U/h) + 128 (W/x)
#define NTAG 9

typedef short v8s __attribute__((ext_vector_type(8)));
typedef float v4f __attribute__((ext_vector_type(4)));
typedef unsigned long long u64t;

__device__ inline unsigned short f2bf(float f){
  union { float f; unsigned u; } v; v.f = f;
  unsigned r = v.u + 0x7FFFu + ((v.u >> 16) & 1u);
  return (unsigned short)(r >> 16);
}
__device__ inline float bf2f(unsigned short h){
  union { unsigned u; float f; } v; v.u = ((unsigned)h) << 16;
  return v.f;
}
__device__ inline float sigm(float x){ return 1.0f/(1.0f + __expf(-x)); }
__device__ inline float tanh_(float x){
  x = fminf(fmaxf(x, -15.0f), 15.0f);
  float e = __expf(2.0f*x);
  return (e - 1.0f)/(e + 1.0f);
}
// z_s swizzle: conflict-free for both MFMA-lane scalar writes and gate float4 reads
__device__ inline int zsw(int row, int col){
  return row*520 + (col ^ ((row & 7) << 2) ^ (((col >> 5) & 3) << 2));
}

// ---------------------------------------------------------------------------
// Pack U/W into UW[d][col'][k] bf16 (col'=unit*4+gate; k<256 U, else W) via
// LDS transpose: coalesced U/W row reads, coalesced UW writes.
// ---------------------------------------------------------------------------
__global__ __launch_bounds__(256) void k_conv(
    const float* __restrict__ Wf, const float* __restrict__ Uf,
    const float* __restrict__ bf_, const float* __restrict__ Wb,
    const float* __restrict__ Ub, const float* __restrict__ bb_,
    unsigned short* __restrict__ UW, float* __restrict__ bpk)
{
  __shared__ unsigned short Ut[NK][72];   // [k][local col], pad 64->72
  int cg64 = blockIdx.x;                  // 0..15 (64-col group)
  int d    = blockIdx.y;
  const float* U = d ? Ub : Uf;
  const float* W = d ? Wb : Wf;
  const float* bias = d ? bb_ : bf_;
  int col0 = cg64*64;
  int tid = threadIdx.x;

  for (int idx = tid; idx < NK*64; idx += 256){
    int k = idx >> 6, cc = idx & 63;
    int gg = cc >> 4, jj = cc & 15;
    int c = gg*HIDn + (col0 >> 2) + jj;       // col = j*4+g  ->  c = g*256+j
    float v = (k < HIDn) ? U[(size_t)k*NG + c] : W[(size_t)(k - HIDn)*NG + c];
    Ut[k][jj*4 + gg] = f2bf(v);
  }
  __syncthreads();
  int cl = tid >> 2, part = tid & 3;
  unsigned short* dst = UW + ((size_t)(d*NG + col0 + cl))*NK + part*96;
  for (int kk = 0; kk < 96; kk += 4){
    int k = part*96 + kk;
    ushort4 v = { Ut[k][cl], Ut[k+1][cl], Ut[k+2][cl], Ut[k+3][cl] };
    *(ushort4*)(dst + kk) = v;
  }
  if (tid < 64)
    bpk[d*NG + col0 + tid] = bias[(tid & 3)*HIDn + (col0 >> 2) + (tid >> 2)];
}

// ---------------------------------------------------------------------------
__global__ void k_lens(const int* __restrict__ text, float* __restrict__ out_lens,
                       int* __restrict__ lens_i)
{
  int b = blockIdx.x, lane = threadIdx.x;
  int cnt = 0;
  for (int s = lane; s < Sn; s += 64) cnt += (text[b*Sn + s] != 0) ? 1 : 0;
  for (int off = 32; off; off >>= 1) cnt += __shfl_down(cnt, off);
  if (lane == 0){ lens_i[b] = cnt; out_lens[b] = (float)cnt; }
}

// ---------------------------------------------------------------------------
// Persistent bidirectional LSTM. grid = (8 groups, 2 col-halves) = 16 blocks,
// 512 threads (8 waves, 2/SIMD, <=256 VGPR -> no spill). Per-wave weights:
// 4 col-tiles x 12 k-tiles v8s = 192 VGPRs, register/AGPR-stationary.
// Cross-block exchange: self-validating tagged u64s (tag = t+1) via relaxed
// agent atomics in d_out scratch; no fences, no flags, no drains.
// ---------------------------------------------------------------------------
__global__ __launch_bounds__(512, 2) void k_lstm(
    const int* __restrict__ text, const float* __restrict__ emb,
    const unsigned short* __restrict__ UW, const float* __restrict__ bpk,
    unsigned short* __restrict__ h_hist, u64t* __restrict__ hbuf)
{
  __shared__ unsigned short A_s[16][392];  // [m][k]: 0..255 h, 256..383 x
  __shared__ float z_s[16*520];            // zsw() layout
  __shared__ int   tok_s[16][Sn];

  int g  = blockIdx.x;                     // d*4 + bg
  int cg = blockIdx.y;                     // col half
  int d  = g >> 2, bg = g & 3;
  int tid = threadIdx.x;
  int wv = tid >> 6, lane = tid & 63, q = lane >> 4, r = lane & 15;
  int m  = tid >> 5, g32 = tid & 31;       // gate/publish mapping

  u64t* pub = hbuf + (size_t)(g*2 + cg)*2048;          // [parity][1024]
  u64t* sub = hbuf + (size_t)(g*2 + (cg^1))*2048;

  // ---- register-stationary weights: cols cg*512 + wv*64 + ct*16 + r ----
  v8s wf[4][12];
  #pragma unroll
  for (int ct = 0; ct < 4; ++ct){
    const unsigned short* base =
        UW + ((size_t)(d*NG + cg*512 + wv*64 + ct*16 + r))*NK;
    #pragma unroll
    for (int kt = 0; kt < 12; ++kt)
      wf[ct][kt] = *(const v8s*)(base + kt*32 + q*8);
  }
  // ---- bias folded into accumulator init (per-lane, per col-tile) ----
  float bz[4];
  #pragma unroll
  for (int ct = 0; ct < 4; ++ct)
    bz[ct] = bpk[d*NG + cg*512 + wv*64 + ct*16 + r];

  // ---- tokens to LDS ----
  for (int idx = tid; idx < 16*Sn; idx += 512){
    int mm = idx >> 9, s = idx & 511;
    tok_s[mm][s] = text[(bg*16 + mm)*Sn + s];
  }
  __syncthreads();

  // ---- stage x for t = 0 ----
  {
    int t0 = d ? (Sn - 1) : 0;
    int tok = tok_s[m][t0];
    float4 x = *(const float4*)(emb + (size_t)tok*EMBn + g32*4);
    ushort4 xb = { f2bf(x.x), f2bf(x.y), f2bf(x.z), f2bf(x.w) };
    *(ushort4*)&A_s[m][HIDn + g32*4] = xb;
  }
  __syncthreads();

  float c_[4] = {0.f, 0.f, 0.f, 0.f};

  #pragma unroll 1
  for (int t = 0; t < Sn; ++t){
    int t_act = d ? (Sn - 1 - t) : t;

    v4f acc[4];
    #pragma unroll
    for (int ct = 0; ct < 4; ++ct) acc[ct] = (v4f){bz[ct], bz[ct], bz[ct], bz[ct]};

    // ---- phase 1: x tiles (kt 8..11) + own-half h tiles ----
    #pragma unroll
    for (int kt = 8; kt < 12; ++kt){
      v8s a = *(const v8s*)&A_s[r][kt*32 + q*8];
      #pragma unroll
      for (int ct = 0; ct < 4; ++ct)
        acc[ct] = __builtin_amdgcn_mfma_f32_16x16x32_bf16(a, wf[ct][kt], acc[ct], 0, 0, 0);
    }
    if (t > 0){
      int kb = cg*4;
      #pragma unroll
      for (int k2 = 0; k2 < 4; ++k2){
        v8s a = *(const v8s*)&A_s[r][(kb + k2)*32 + q*8];
        #pragma unroll
        for (int ct = 0; ct < 4; ++ct)
          acc[ct] = __builtin_amdgcn_mfma_f32_16x16x32_bf16(a, wf[ct][kb + k2], acc[ct], 0, 0, 0);
      }
      // ---- poll partner h_{t-1}: tag == t (published as t-1+1) ----
      unsigned tgt = (unsigned)t;
      u64t* src = sub + (size_t)((t - 1) & 1)*1024 + (m*32 + g32)*2;
      u64t a0, a1;
      do { a0 = __hip_atomic_load(src, __ATOMIC_RELAXED, __HIP_MEMORY_SCOPE_AGENT); }
      while ((unsigned)(a0 & 0xFFFFu) != tgt);
      do { a1 = __hip_atomic_load(src + 1, __ATOMIC_RELAXED, __HIP_MEMORY_SCOPE_AGENT); }
      while ((unsigned)(a1 & 0xFFFFu) != tgt);
      ushort4 hv = { (unsigned short)(a0 >> 16), (unsigned short)(a0 >> 32),
                     (unsigned short)(a1 >> 16), (unsigned short)(a1 >> 32) };
      *(ushort4*)&A_s[m][(cg^1)*128 + g32*4] = hv;
    }
    __syncthreads();   // B_A: partner half staged

    if (t > 0){
      int kb = (cg^1)*4;
      #pragma unroll
      for (int k2 = 0; k2 < 4; ++k2){
        v8s a = *(const v8s*)&A_s[r][(kb + k2)*32 + q*8];
        #pragma unroll
        for (int ct = 0; ct < 4; ++ct)
          acc[ct] = __builtin_amdgcn_mfma_f32_16x16x32_bf16(a, wf[ct][kb + k2], acc[ct], 0, 0, 0);
      }
    }
    // ---- z -> LDS (swizzled, conflict-free) ----
    #pragma unroll
    for (int ct = 0; ct < 4; ++ct){
      int col = wv*64 + ct*16 + r;
      #pragma unroll
      for (int i = 0; i < 4; ++i)
        z_s[zsw(q*4 + i, col)] = acc[ct][i];
    }
    __syncthreads();   // B_z

    // ---- gates: thread (m, g32) owns local units g32*4 .. +3 ----
    unsigned short hsh[4];
    #pragma unroll
    for (int i = 0; i < 4; ++i){
      int cbase = g32*16 + i*4;
      float4 z4 = *(const float4*)&z_s[zsw(m, cbase)];
      float ii = sigm(z4.x), ff = sigm(z4.y);
      float gg = tanh_(z4.z), oo = sigm(z4.w);
      c_[i] = ff*c_[i] + ii*gg;
      hsh[i] = f2bf(oo*tanh_(c_[i]));
    }
    // ---- publish (tagged, fire-and-forget) ----
    {
      u64t tag = (u64t)(t + 1);
      u64t lo = tag | ((u64t)hsh[0] << 16) | ((u64t)hsh[1] << 32);
      u64t hi = tag | ((u64t)hsh[2] << 16) | ((u64t)hsh[3] << 32);
      u64t* dst = pub + (size_t)(t & 1)*1024 + (m*32 + g32)*2;
      __hip_atomic_store(dst,     lo, __ATOMIC_RELAXED, __HIP_MEMORY_SCOPE_AGENT);
      __hip_atomic_store(dst + 1, hi, __ATOMIC_RELAXED, __HIP_MEMORY_SCOPE_AGENT);
    }
    // ---- own h -> A_s + h_hist ----
    {
      ushort4 hv = { hsh[0], hsh[1], hsh[2], hsh[3] };
      *(ushort4*)&A_s[m][cg*128 + g32*4] = hv;
      u64t hp = (u64t)hsh[0] | ((u64t)hsh[1] << 16) |
                ((u64t)hsh[2] << 32) | ((u64t)hsh[3] << 48);
      *(u64t*)(h_hist + ((size_t)(d*Sn + t_act)*Bn + bg*16 + m)*HIDn
               + cg*128 + g32*4) = hp;
    }
    // ---- prefetch + stage x_{t+1} ----
    if (t < Sn - 1){
      int tn = d ? (Sn - 2 - t) : (t + 1);
      int tok = tok_s[m][tn];
      float4 x = *(const float4*)(emb + (size_t)tok*EMBn + g32*4);
      ushort4 xb = { f2bf(x.x), f2bf(x.y), f2bf(x.z), f2bf(x.w) };
      *(ushort4*)&A_s[m][HIDn + g32*4] = xb;
    }
    __syncthreads();   // B_end
  }
}

// ---------------------------------------------------------------------------
__global__ __launch_bounds__(256) void k_logits(
    const unsigned short* __restrict__ h_hist, const float* __restrict__ Wd,
    const float* __restrict__ bd, float* __restrict__ out)
{
  __shared__ float Wd_s[2*HIDn*NTAG];
  __shared__ float bd_s[NTAG];
  for (int i = threadIdx.x; i < 2*HIDn*NTAG; i += 256) Wd_s[i] = Wd[i];
  if (threadIdx.x < NTAG) bd_s[threadIdx.x] = bd[threadIdx.x];
  __syncthreads();

  int n = blockIdx.x*256 + threadIdx.x;   // n = b*512 + s
  int b = n >> 9, s = n & 511;
  float acc[NTAG];
  #pragma unroll
  for (int k = 0; k < NTAG; ++k) acc[k] = bd_s[k];

  const uint4* hf = (const uint4*)(h_hist + ((size_t)s*Bn + b)*HIDn);
  const uint4* hb = (const uint4*)(h_hist + ((size_t)(Sn + s)*Bn + b)*HIDn);
  #pragma unroll 4
  for (int ch = 0; ch < HIDn/8; ++ch){
    uint4 vf = hf[ch], vb = hb[ch];
    unsigned int wsv[8] = {vf.x, vf.y, vf.z, vf.w, vb.x, vb.y, vb.z, vb.w};
    #pragma unroll
    for (int half = 0; half < 2; ++half){
      int jbase = half*HIDn + ch*8;
      #pragma unroll
      for (int e = 0; e < 4; ++e){
        unsigned int u = wsv[half*4 + e];
        float hlo = bf2f((unsigned short)(u & 0xFFFF));
        float hhi = bf2f((unsigned short)(u >> 16));
        const float* w0 = &Wd_s[(jbase + e*2    )*NTAG];
        const float* w1 = &Wd_s[(jbase + e*2 + 1)*NTAG];
        #pragma unroll
        for (int k = 0; k < NTAG; ++k) acc[k] += hlo*w0[k] + hhi*w1[k];
      }
    }
  }
  float* o = out + (size_t)n*NTAG;
  #pragma unroll
  for (int k = 0; k < NTAG; ++k) o[k] = acc[k];
}

// ---------------------------------------------------------------------------
__global__ __launch_bounds__(64) void k_crf(
    const float* __restrict__ logits, const int* __restrict__ labels,
    const float* __restrict__ trans, const int* __restrict__ lens_i,
    float* __restrict__ out_ll)
{
  int b = blockIdx.x, lane = threadIdx.x;
  int len = lens_i[b];
  const float* lg = logits + (size_t)b*Sn*NTAG;
  const int* lab = labels + b*Sn;

  float sc = 0.f;
  for (int s = lane; s < Sn; s += 64){
    if (s < len)     sc += lg[s*NTAG + lab[s]];
    if (s < len - 1) sc += trans[lab[s]*NTAG + lab[s+1]];
  }
  for (int off = 32; off; off >>= 1) sc += __shfl_down(sc, off);
  sc = __shfl(sc, 0);

  int j = (lane < NTAG) ? lane : (NTAG - 1);
  float Tj[NTAG];
  #pragma unroll
  for (int i = 0; i < NTAG; ++i) Tj[i] = trans[i*NTAG + j];
  float alpha = lg[j];
  float nxt = lg[NTAG + j];
  for (int t = 1; t < Sn; ++t){
    float cur = nxt;
    if (t < Sn - 1) nxt = lg[(t+1)*NTAG + j];
    float v[NTAG]; float mx;
    v[0] = __shfl(alpha, 0) + Tj[0]; mx = v[0];
    #pragma unroll
    for (int i = 1; i < NTAG; ++i){ v[i] = __shfl(alpha, i) + Tj[i]; mx = fmaxf(mx, v[i]); }
    float ssum = 0.f;
    #pragma unroll
    for (int i = 0; i < NTAG; ++i) ssum += __expf(v[i] - mx);
    float na = mx + __logf(ssum) + cur;
    if (t < len) alpha = na;
  }
  float m2 = __shfl(alpha, 0);
  #pragma unroll
  for (int i = 1; i < NTAG; ++i) m2 = fmaxf(m2, __shfl(alpha, i));
  float s2 = 0.f;
  #pragma unroll
  for (int i = 0; i < NTAG; ++i) s2 += __expf(__shfl(alpha, i) - m2);
  float ln = m2 + __logf(s2);
  if (lane == 0) out_ll[b] = sc - ln;
}

// ---------------------------------------------------------------------------
extern "C" void kernel_launch(void* const* d_in, const int* in_sizes, int n_in,
                              void* d_out, int out_size, void* d_ws, size_t ws_size,
                              hipStream_t stream)
{
  const int*   text   = (const int*)  d_in[0];
  const int*   labels = (const int*)  d_in[1];
  const float* emb    = (const float*)d_in[2];
  const float* W_f    = (const float*)d_in[3];
  const float* U_f    = (const float*)d_in[4];
  const float* b_f    = (const float*)d_in[5];
  const float* W_b    = (const float*)d_in[6];
  const float* U_b    = (const float*)d_in[7];
  const float* b_b    = (const float*)d_in[8];
  const float* W_d    = (const float*)d_in[9];
  const float* b_d    = (const float*)d_in[10];
  const float* trans  = (const float*)d_in[11];
  float* out = (float*)d_out;                  // [logits 294912][lens 64][ll 64]

  // h-exchange scratch lives in d_out's logits area (256 KiB < 1.18 MiB),
  // overwritten by k_logits afterwards. Tags: 0x0000 (memset) and 0xAAAA
  // (poison) never match tag = t+1 in [1, 512].
  u64t* hbuf = (u64t*)d_out;

  char* w = (char*)d_ws;
  int*            lens_i = (int*)w;                          // 256 B
  float*          bpk    = (float*)(w + 256);                // 8 KiB
  unsigned short* UW     = (unsigned short*)(w + 8448);      // 1.5 MiB
  unsigned short* h_hist = (unsigned short*)(w + 1581312);   // 32 MiB

  hipLaunchKernelGGL(k_conv, dim3(16, 2), dim3(256), 0, stream,
                     W_f, U_f, b_f, W_b, U_b, b_b, UW, bpk);
  hipLaunchKernelGGL(k_lens, dim3(Bn), dim3(64), 0, stream,
                     text, out + Bn*Sn*NTAG, lens_i);

  void* args[] = { (void*)&text, (void*)&emb, (void*)&UW, (void*)&bpk,
                   (void*)&h_hist, (void*)&hbuf };
  hipLaunchCooperativeKernel((const void*)k_lstm, dim3(8, 2), dim3(512),
                             args, 0, stream);

  hipLaunchKernelGGL(k_logits, dim3(Bn*Sn/256), dim3(256), 0, stream,
                     h_hist, W_d, b_d, out);
  hipLaunchKernelGGL(k_crf, dim3(Bn), dim3(64), 0, stream,
                     out, labels, trans, lens_i, out + Bn*Sn*NTAG + Bn);
}

// Round 5
// 2564.665 us; speedup vs baseline: 2.7069x; 2.7069x over previous
//
#include <hip/hip_runtime.h>
#include <math.h>

#define Bn   64
#define Sn   512
#define EMBn 128
#define HIDn 256
#define NG   1024   // 4*HID
#define NK   384    // 256 (U/h) + 128 (W/x)
#define NTAG 9

typedef short v8s __attribute__((ext_vector_type(8)));
typedef float v4f __attribute__((ext_vector_type(4)));
typedef unsigned long long u64t;

__device__ inline unsigned short f2bf(float f){
  union { float f; unsigned u; } v; v.f = f;
  unsigned r = v.u + 0x7FFFu + ((v.u >> 16) & 1u);
  return (unsigned short)(r >> 16);
}
__device__ inline float bf2f(unsigned short h){
  union { unsigned u; float f; } v; v.u = ((unsigned)h) << 16;
  return v.f;
}
__device__ inline float sigm(float x){ return 1.0f/(1.0f + __expf(-x)); }
__device__ inline float tanh_(float x){
  x = fminf(fmaxf(x, -15.0f), 15.0f);
  float e = __expf(2.0f*x);
  return (e - 1.0f)/(e + 1.0f);
}
// z_s swizzle: write side 2-way max (free per m136)
__device__ inline int zsw(int row, int col){
  return row*520 + (col ^ ((row & 7) << 2) ^ (((col >> 5) & 3) << 2));
}

// ---------------------------------------------------------------------------
// Pack U/W into UW[d][col'][k] bf16 (col'=unit*4+gate; k<256 U, else W) via
// LDS transpose: coalesced U/W row reads, coalesced UW writes.
// ---------------------------------------------------------------------------
__global__ __launch_bounds__(256) void k_conv(
    const float* __restrict__ Wf, const float* __restrict__ Uf,
    const float* __restrict__ bf_, const float* __restrict__ Wb,
    const float* __restrict__ Ub, const float* __restrict__ bb_,
    unsigned short* __restrict__ UW, float* __restrict__ bpk)
{
  __shared__ unsigned short Ut[NK][72];   // [k][local col], pad 64->72
  int cg64 = blockIdx.x;                  // 0..15 (64-col group)
  int d    = blockIdx.y;
  const float* U = d ? Ub : Uf;
  const float* W = d ? Wb : Wf;
  const float* bias = d ? bb_ : bf_;
  int col0 = cg64*64;
  int tid = threadIdx.x;

  for (int idx = tid; idx < NK*64; idx += 256){
    int k = idx >> 6, cc = idx & 63;
    int gg = cc >> 4, jj = cc & 15;
    int c = gg*HIDn + (col0 >> 2) + jj;       // col = j*4+g  ->  c = g*256+j
    float v = (k < HIDn) ? U[(size_t)k*NG + c] : W[(size_t)(k - HIDn)*NG + c];
    Ut[k][jj*4 + gg] = f2bf(v);
  }
  __syncthreads();
  int cl = tid >> 2, part = tid & 3;
  unsigned short* dst = UW + ((size_t)(d*NG + col0 + cl))*NK + part*96;
  for (int kk = 0; kk < 96; kk += 4){
    int k = part*96 + kk;
    ushort4 v = { Ut[k][cl], Ut[k+1][cl], Ut[k+2][cl], Ut[k+3][cl] };
    *(ushort4*)(dst + kk) = v;
  }
  if (tid < 64)
    bpk[d*NG + col0 + tid] = bias[(tid & 3)*HIDn + (col0 >> 2) + (tid >> 2)];
}

// ---------------------------------------------------------------------------
__global__ void k_lens(const int* __restrict__ text, float* __restrict__ out_lens,
                       int* __restrict__ lens_i)
{
  int b = blockIdx.x, lane = threadIdx.x;
  int cnt = 0;
  for (int s = lane; s < Sn; s += 64) cnt += (text[b*Sn + s] != 0) ? 1 : 0;
  for (int off = 32; off; off >>= 1) cnt += __shfl_down(cnt, off);
  if (lane == 0){ lens_i[b] = cnt; out_lens[b] = (float)cnt; }
}

// ---------------------------------------------------------------------------
// Persistent bidirectional LSTM. grid = (8 groups, 2 col-halves) = 16 blocks,
// 512 threads. Per-wave weights wf[4][12]: ALL array indices compile-time
// (j-slot -> k-tile mapping resolved at load: j 0..3 = x tiles 8..11,
// j 4..7 = own-half tiles cg*4.., j 8..11 = partner-half (cg^1)*4.. —
// runtime only in the ADDRESS, never the register-array index -> SROA keeps
// 192 weight VGPRs resident; round-4's wf[ct][kb+k2] runtime index demoted
// the whole array to scratch (VGPR=72, 166 MB spill traffic).
// Cross-block exchange: self-validating tagged u64s (tag = t+1) via relaxed
// agent atomics in d_out scratch; poll loops throttled with s_sleep.
// ---------------------------------------------------------------------------
__global__ __launch_bounds__(512, 2) void k_lstm(
    const int* __restrict__ text, const float* __restrict__ emb,
    const unsigned short* __restrict__ UW, const float* __restrict__ bpk,
    unsigned short* __restrict__ h_hist, u64t* __restrict__ hbuf)
{
  __shared__ unsigned short A_s[16][392];  // [m][k]: 0..255 h, 256..383 x
  __shared__ float z_s[16*520];            // zsw() layout
  __shared__ int   tok_s[16][Sn];

  int g  = blockIdx.x;                     // d*4 + bg
  int cg = blockIdx.y;                     // col half
  int d  = g >> 2, bg = g & 3;
  int tid = threadIdx.x;
  int wv = tid >> 6, lane = tid & 63, q = lane >> 4, r = lane & 15;
  int m  = tid >> 5, g32 = tid & 31;       // gate/publish mapping

  u64t* pub = hbuf + (size_t)(g*2 + cg)*2048;          // [parity][1024]
  u64t* sub = hbuf + (size_t)(g*2 + (cg^1))*2048;

  // ---- register-stationary weights, compile-time slot indices ----
  v8s wf[4][12];
  #pragma unroll
  for (int ct = 0; ct < 4; ++ct){
    const unsigned short* base =
        UW + ((size_t)(d*NG + cg*512 + wv*64 + ct*16 + r))*NK;
    #pragma unroll
    for (int j = 0; j < 4; ++j)                     // x tiles (k 256..383)
      wf[ct][j] = *(const v8s*)(base + (8 + j)*32 + q*8);
    #pragma unroll
    for (int j = 0; j < 4; ++j)                     // own h half
      wf[ct][4 + j] = *(const v8s*)(base + (cg*4 + j)*32 + q*8);
    #pragma unroll
    for (int j = 0; j < 4; ++j)                     // partner h half
      wf[ct][8 + j] = *(const v8s*)(base + ((cg^1)*4 + j)*32 + q*8);
  }
  // ---- bias folded into accumulator init ----
  float bz[4];
  #pragma unroll
  for (int ct = 0; ct < 4; ++ct)
    bz[ct] = bpk[d*NG + cg*512 + wv*64 + ct*16 + r];

  // ---- tokens to LDS ----
  for (int idx = tid; idx < 16*Sn; idx += 512){
    int mm = idx >> 9, s = idx & 511;
    tok_s[mm][s] = text[(bg*16 + mm)*Sn + s];
  }
  __syncthreads();

  // ---- stage x for t = 0 ----
  {
    int t0 = d ? (Sn - 1) : 0;
    int tok = tok_s[m][t0];
    float4 x = *(const float4*)(emb + (size_t)tok*EMBn + g32*4);
    ushort4 xb = { f2bf(x.x), f2bf(x.y), f2bf(x.z), f2bf(x.w) };
    *(ushort4*)&A_s[m][HIDn + g32*4] = xb;
  }
  __syncthreads();

  float c_[4] = {0.f, 0.f, 0.f, 0.f};

  #pragma unroll 1
  for (int t = 0; t < Sn; ++t){
    int t_act = d ? (Sn - 1 - t) : t;

    v4f acc[4];
    #pragma unroll
    for (int ct = 0; ct < 4; ++ct) acc[ct] = (v4f){bz[ct], bz[ct], bz[ct], bz[ct]};

    // ---- phase 1a: x tiles (slots 0..3) ----
    #pragma unroll
    for (int j = 0; j < 4; ++j){
      v8s a = *(const v8s*)&A_s[r][(8 + j)*32 + HIDn - 256 + 256 + q*8 - 256 + 0];
      // (A_s x region starts at HIDn: element (256 + j*32 + q*8))
      a = *(const v8s*)&A_s[r][256 + j*32 + q*8];
      #pragma unroll
      for (int ct = 0; ct < 4; ++ct)
        acc[ct] = __builtin_amdgcn_mfma_f32_16x16x32_bf16(a, wf[ct][j], acc[ct], 0, 0, 0);
    }
    if (t > 0){
      // ---- phase 1b: own h half (slots 4..7; runtime LDS addr, const reg idx)
      #pragma unroll
      for (int j = 0; j < 4; ++j){
        v8s a = *(const v8s*)&A_s[r][cg*128 + j*32 + q*8];
        #pragma unroll
        for (int ct = 0; ct < 4; ++ct)
          acc[ct] = __builtin_amdgcn_mfma_f32_16x16x32_bf16(a, wf[ct][4 + j], acc[ct], 0, 0, 0);
      }
      // ---- poll partner h_{t-1}: tag == t; throttled spin ----
      unsigned tgt = (unsigned)t;
      u64t* src = sub + (size_t)((t - 1) & 1)*1024 + (m*32 + g32)*2;
      u64t a0 = __hip_atomic_load(src, __ATOMIC_RELAXED, __HIP_MEMORY_SCOPE_AGENT);
      while ((unsigned)(a0 & 0xFFFFu) != tgt){
        __builtin_amdgcn_s_sleep(1);
        a0 = __hip_atomic_load(src, __ATOMIC_RELAXED, __HIP_MEMORY_SCOPE_AGENT);
      }
      u64t a1 = __hip_atomic_load(src + 1, __ATOMIC_RELAXED, __HIP_MEMORY_SCOPE_AGENT);
      while ((unsigned)(a1 & 0xFFFFu) != tgt){
        __builtin_amdgcn_s_sleep(1);
        a1 = __hip_atomic_load(src + 1, __ATOMIC_RELAXED, __HIP_MEMORY_SCOPE_AGENT);
      }
      ushort4 hv = { (unsigned short)(a0 >> 16), (unsigned short)(a0 >> 32),
                     (unsigned short)(a1 >> 16), (unsigned short)(a1 >> 32) };
      *(ushort4*)&A_s[m][(cg^1)*128 + g32*4] = hv;
    }
    __syncthreads();   // B_A: partner half staged

    if (t > 0){
      // ---- phase 2: partner h half (slots 8..11) ----
      #pragma unroll
      for (int j = 0; j < 4; ++j){
        v8s a = *(const v8s*)&A_s[r][(cg^1)*128 + j*32 + q*8];
        #pragma unroll
        for (int ct = 0; ct < 4; ++ct)
          acc[ct] = __builtin_amdgcn_mfma_f32_16x16x32_bf16(a, wf[ct][8 + j], acc[ct], 0, 0, 0);
      }
    }
    // ---- z -> LDS (swizzled) ----
    #pragma unroll
    for (int ct = 0; ct < 4; ++ct){
      int col = wv*64 + ct*16 + r;
      #pragma unroll
      for (int i = 0; i < 4; ++i)
        z_s[zsw(q*4 + i, col)] = acc[ct][i];
    }
    __syncthreads();   // B_z

    // ---- gates: thread (m, g32) owns local units g32*4 .. +3 ----
    unsigned short hsh[4];
    #pragma unroll
    for (int i = 0; i < 4; ++i){
      int cbase = g32*16 + i*4;
      float4 z4 = *(const float4*)&z_s[zsw(m, cbase)];
      float ii = sigm(z4.x), ff = sigm(z4.y);
      float gg = tanh_(z4.z), oo = sigm(z4.w);
      c_[i] = ff*c_[i] + ii*gg;
      hsh[i] = f2bf(oo*tanh_(c_[i]));
    }
    // ---- publish FIRST (partner's critical path) ----
    {
      u64t tag = (u64t)(t + 1);
      u64t lo = tag | ((u64t)hsh[0] << 16) | ((u64t)hsh[1] << 32);
      u64t hi = tag | ((u64t)hsh[2] << 16) | ((u64t)hsh[3] << 32);
      u64t* dst = pub + (size_t)(t & 1)*1024 + (m*32 + g32)*2;
      __hip_atomic_store(dst,     lo, __ATOMIC_RELAXED, __HIP_MEMORY_SCOPE_AGENT);
      __hip_atomic_store(dst + 1, hi, __ATOMIC_RELAXED, __HIP_MEMORY_SCOPE_AGENT);
    }
    // ---- own h -> A_s + h_hist ----
    {
      ushort4 hv = { hsh[0], hsh[1], hsh[2], hsh[3] };
      *(ushort4*)&A_s[m][cg*128 + g32*4] = hv;
      u64t hp = (u64t)hsh[0] | ((u64t)hsh[1] << 16) |
                ((u64t)hsh[2] << 32) | ((u64t)hsh[3] << 48);
      *(u64t*)(h_hist + ((size_t)(d*Sn + t_act)*Bn + bg*16 + m)*HIDn
               + cg*128 + g32*4) = hp;
    }
    // ---- prefetch + stage x_{t+1} ----
    if (t < Sn - 1){
      int tn = d ? (Sn - 2 - t) : (t + 1);
      int tok = tok_s[m][tn];
      float4 x = *(const float4*)(emb + (size_t)tok*EMBn + g32*4);
      ushort4 xb = { f2bf(x.x), f2bf(x.y), f2bf(x.z), f2bf(x.w) };
      *(ushort4*)&A_s[m][HIDn + g32*4] = xb;
    }
    __syncthreads();   // B_end
  }
}

// ---------------------------------------------------------------------------
__global__ __launch_bounds__(256) void k_logits(
    const unsigned short* __restrict__ h_hist, const float* __restrict__ Wd,
    const float* __restrict__ bd, float* __restrict__ out)
{
  __shared__ float Wd_s[2*HIDn*NTAG];
  __shared__ float bd_s[NTAG];
  for (int i = threadIdx.x; i < 2*HIDn*NTAG; i += 256) Wd_s[i] = Wd[i];
  if (threadIdx.x < NTAG) bd_s[threadIdx.x] = bd[threadIdx.x];
  __syncthreads();

  int n = blockIdx.x*256 + threadIdx.x;   // n = b*512 + s
  int b = n >> 9, s = n & 511;
  float acc[NTAG];
  #pragma unroll
  for (int k = 0; k < NTAG; ++k) acc[k] = bd_s[k];

  const uint4* hf = (const uint4*)(h_hist + ((size_t)s*Bn + b)*HIDn);
  const uint4* hb = (const uint4*)(h_hist + ((size_t)(Sn + s)*Bn + b)*HIDn);
  #pragma unroll 4
  for (int ch = 0; ch < HIDn/8; ++ch){
    uint4 vf = hf[ch], vb = hb[ch];
    unsigned int wsv[8] = {vf.x, vf.y, vf.z, vf.w, vb.x, vb.y, vb.z, vb.w};
    #pragma unroll
    for (int half = 0; half < 2; ++half){
      int jbase = half*HIDn + ch*8;
      #pragma unroll
      for (int e = 0; e < 4; ++e){
        unsigned int u = wsv[half*4 + e];
        float hlo = bf2f((unsigned short)(u & 0xFFFF));
        float hhi = bf2f((unsigned short)(u >> 16));
        const float* w0 = &Wd_s[(jbase + e*2    )*NTAG];
        const float* w1 = &Wd_s[(jbase + e*2 + 1)*NTAG];
        #pragma unroll
        for (int k = 0; k < NTAG; ++k) acc[k] += hlo*w0[k] + hhi*w1[k];
      }
    }
  }
  float* o = out + (size_t)n*NTAG;
  #pragma unroll
  for (int k = 0; k < NTAG; ++k) o[k] = acc[k];
}

// ---------------------------------------------------------------------------
__global__ __launch_bounds__(64) void k_crf(
    const float* __restrict__ logits, const int* __restrict__ labels,
    const float* __restrict__ trans, const int* __restrict__ lens_i,
    float* __restrict__ out_ll)
{
  int b = blockIdx.x, lane = threadIdx.x;
  int len = lens_i[b];
  const float* lg = logits + (size_t)b*Sn*NTAG;
  const int* lab = labels + b*Sn;

  float sc = 0.f;
  for (int s = lane; s < Sn; s += 64){
    if (s < len)     sc += lg[s*NTAG + lab[s]];
    if (s < len - 1) sc += trans[lab[s]*NTAG + lab[s+1]];
  }
  for (int off = 32; off; off >>= 1) sc += __shfl_down(sc, off);
  sc = __shfl(sc, 0);

  int j = (lane < NTAG) ? lane : (NTAG - 1);
  float Tj[NTAG];
  #pragma unroll
  for (int i = 0; i < NTAG; ++i) Tj[i] = trans[i*NTAG + j];
  float alpha = lg[j];
  float nxt = lg[NTAG + j];
  for (int t = 1; t < Sn; ++t){
    float cur = nxt;
    if (t < Sn - 1) nxt = lg[(t+1)*NTAG + j];
    float v[NTAG]; float mx;
    v[0] = __shfl(alpha, 0) + Tj[0]; mx = v[0];
    #pragma unroll
    for (int i = 1; i < NTAG; ++i){ v[i] = __shfl(alpha, i) + Tj[i]; mx = fmaxf(mx, v[i]); }
    float ssum = 0.f;
    #pragma unroll
    for (int i = 0; i < NTAG; ++i) ssum += __expf(v[i] - mx);
    float na = mx + __logf(ssum) + cur;
    if (t < len) alpha = na;
  }
  float m2 = __shfl(alpha, 0);
  #pragma unroll
  for (int i = 1; i < NTAG; ++i) m2 = fmaxf(m2, __shfl(alpha, i));
  float s2 = 0.f;
  #pragma unroll
  for (int i = 0; i < NTAG; ++i) s2 += __expf(__shfl(alpha, i) - m2);
  float ln = m2 + __logf(s2);
  if (lane == 0) out_ll[b] = sc - ln;
}

// ---------------------------------------------------------------------------
extern "C" void kernel_launch(void* const* d_in, const int* in_sizes, int n_in,
                              void* d_out, int out_size, void* d_ws, size_t ws_size,
                              hipStream_t stream)
{
  const int*   text   = (const int*)  d_in[0];
  const int*   labels = (const int*)  d_in[1];
  const float* emb    = (const float*)d_in[2];
  const float* W_f    = (const float*)d_in[3];
  const float* U_f    = (const float*)d_in[4];
  const float* b_f    = (const float*)d_in[5];
  const float* W_b    = (const float*)d_in[6];
  const float* U_b    = (const float*)d_in[7];
  const float* b_b    = (const float*)d_in[8];
  const float* W_d    = (const float*)d_in[9];
  const float* b_d    = (const float*)d_in[10];
  const float* trans  = (const float*)d_in[11];
  float* out = (float*)d_out;                  // [logits 294912][lens 64][ll 64]

  // h-exchange scratch in d_out's logits area (256 KiB < 1.18 MiB),
  // fully overwritten by k_logits afterwards. Tags: 0x0000 (memset) and
  // 0xAAAA (poison) never match tag = t+1 in [1, 512].
  u64t* hbuf = (u64t*)d_out;

  char* w = (char*)d_ws;
  int*            lens_i = (int*)w;                          // 256 B
  float*          bpk    = (float*)(w + 256);                // 8 KiB
  unsigned short* UW     = (unsigned short*)(w + 8448);      // 1.5 MiB
  unsigned short* h_hist = (unsigned short*)(w + 1581312);   // 32 MiB

  hipLaunchKernelGGL(k_conv, dim3(16, 2), dim3(256), 0, stream,
                     W_f, U_f, b_f, W_b, U_b, b_b, UW, bpk);
  hipLaunchKernelGGL(k_lens, dim3(Bn), dim3(64), 0, stream,
                     text, out + Bn*Sn*NTAG, lens_i);

  void* args[] = { (void*)&text, (void*)&emb, (void*)&UW, (void*)&bpk,
                   (void*)&h_hist, (void*)&hbuf };
  hipLaunchCooperativeKernel((const void*)k_lstm, dim3(8, 2), dim3(512),
                             args, 0, stream);

  hipLaunchKernelGGL(k_logits, dim3(Bn*Sn/256), dim3(256), 0, stream,
                     h_hist, W_d, b_d, out);
  hipLaunchKernelGGL(k_crf, dim3(Bn), dim3(64), 0, stream,
                     out, labels, trans, lens_i, out + Bn*Sn*NTAG + Bn);
}

// Round 6
// 2007.158 us; speedup vs baseline: 3.4588x; 1.2778x over previous
//
#include <hip/hip_runtime.h>
#include <math.h>

#define Bn   64
#define Sn   512
#define EMBn 128
#define HIDn 256
#define NG   1024   // 4*HID
#define NK   384    // packed UW row: k<256 = U, k>=256 = W
#define NTAG 9

typedef short v8s __attribute__((ext_vector_type(8)));
typedef float v4f __attribute__((ext_vector_type(4)));
typedef unsigned long long u64t;

__device__ inline unsigned short f2bf(float f){
  union { float f; unsigned u; } v; v.f = f;
  unsigned r = v.u + 0x7FFFu + ((v.u >> 16) & 1u);
  return (unsigned short)(r >> 16);
}
__device__ inline float bf2f(unsigned short h){
  union { unsigned u; float f; } v; v.u = ((unsigned)h) << 16;
  return v.f;
}
// manual OCP e4m3fn (avoid header dependence)
__device__ inline unsigned char f8e(float f){
  union { float f; unsigned u; } v; v.f = f;
  unsigned s = (v.u >> 31) << 7;
  float af = fabsf(f);
  if (af > 448.f) af = 448.f;
  if (af < 0.015625f){                      // subnormal: m * 2^-9
    int m = (int)(af*512.f + 0.5f);
    return (unsigned char)(s | m);          // m==8 naturally becomes 0x08 = 2^-6
  }
  union { float f; unsigned u; } w; w.f = af;
  unsigned rb = w.u + 0x00080000u;          // round mantissa at bit 20
  int exp = (int)((rb >> 23) & 255) - 127;
  if (exp > 8) return (unsigned char)(s | 0x7E);   // clamp 448
  return (unsigned char)(s | ((exp + 7) << 3) | ((rb >> 20) & 7));
}
__device__ inline float f8d(unsigned char u){
  if ((u & 0x78) == 0){
    float m = (float)(u & 7) * 0.001953125f;
    return (u & 0x80) ? -m : m;
  }
  union { unsigned b; float f; } v;
  v.b = ((unsigned)(u & 0x80) << 24) | ((((u >> 3) & 15) + 120) << 23)
        | ((unsigned)(u & 7) << 20);
  return v.f;
}
__device__ inline float sigm(float x){ return 1.0f/(1.0f + __expf(-x)); }
__device__ inline float tanh_(float x){
  x = fminf(fmaxf(x, -15.0f), 15.0f);
  float e = __expf(2.0f*x);
  return (e - 1.0f)/(e + 1.0f);
}
__device__ inline int zsw(int row, int col){
  return row*520 + (col ^ ((row & 7) << 2) ^ (((col >> 5) & 3) << 2));
}

// ---------------------------------------------------------------------------
// Pack U/W into UW[d][col'][k] bf16 (col'=unit*4+gate) + packed bias.
// ---------------------------------------------------------------------------
__global__ __launch_bounds__(256) void k_conv(
    const float* __restrict__ Wf, const float* __restrict__ Uf,
    const float* __restrict__ bf_, const float* __restrict__ Wb,
    const float* __restrict__ Ub, const float* __restrict__ bb_,
    unsigned short* __restrict__ UW, float* __restrict__ bpk)
{
  __shared__ unsigned short Ut[NK][72];
  int cg64 = blockIdx.x, d = blockIdx.y;
  const float* U = d ? Ub : Uf;
  const float* W = d ? Wb : Wf;
  const float* bias = d ? bb_ : bf_;
  int col0 = cg64*64;
  int tid = threadIdx.x;

  for (int idx = tid; idx < NK*64; idx += 256){
    int k = idx >> 6, cc = idx & 63;
    int gg = cc >> 4, jj = cc & 15;
    int c = gg*HIDn + (col0 >> 2) + jj;
    float v = (k < HIDn) ? U[(size_t)k*NG + c] : W[(size_t)(k - HIDn)*NG + c];
    Ut[k][jj*4 + gg] = f2bf(v);
  }
  __syncthreads();
  int cl = tid >> 2, part = tid & 3;
  unsigned short* dst = UW + ((size_t)(d*NG + col0 + cl))*NK + part*96;
  for (int kk = 0; kk < 96; kk += 4){
    int k = part*96 + kk;
    ushort4 v = { Ut[k][cl], Ut[k+1][cl], Ut[k+2][cl], Ut[k+3][cl] };
    *(ushort4*)(dst + kk) = v;
  }
  if (tid < 64)
    bpk[d*NG + col0 + tid] = bias[(tid & 3)*HIDn + (col0 >> 2) + (tid >> 2)];
}

// ---------------------------------------------------------------------------
__global__ void k_lens(const int* __restrict__ text, float* __restrict__ out_lens,
                       int* __restrict__ lens_i)
{
  int b = blockIdx.x, lane = threadIdx.x;
  int cnt = 0;
  for (int s = lane; s < Sn; s += 64) cnt += (text[b*Sn + s] != 0) ? 1 : 0;
  for (int off = 32; off; off >>= 1) cnt += __shfl_down(cnt, off);
  if (lane == 0){ lens_i[b] = cnt; out_lens[b] = (float)cnt; }
}

// ---------------------------------------------------------------------------
// Precompute xz[d][s][b][col'] = emb[text[b][s]] @ W + bias (bf16 or fp8).
// grid = (2048 M-tiles of 16 tokens, 4 col-groups of 256, 2 dirs), 256 thr.
// Fully parallel MFMA GEMM; removes x-projection + emb gather from the
// recurrent loop so k_lstm's weights fit in registers (the r3-r5 spill fix).
// ---------------------------------------------------------------------------
__global__ __launch_bounds__(256) void k_xw(
    const int* __restrict__ text, const float* __restrict__ emb,
    const unsigned short* __restrict__ UW, const float* __restrict__ bpk,
    void* __restrict__ xz_v, int use_fp8)
{
  __shared__ unsigned short A_x[16][136];
  int n0 = blockIdx.x*16;            // token tile; token n = s*64 + b
  int cgrp = blockIdx.y, d = blockIdx.z;
  int s = n0 >> 6, b0 = n0 & 63;
  int tid = threadIdx.x;
  int wv = tid >> 6, lane = tid & 63, q = lane >> 4, r = lane & 15;

  {
    int mm = tid >> 4, k8 = (tid & 15)*8;
    int tok = text[(b0 + mm)*Sn + s];
    float4 x0 = *(const float4*)(emb + (size_t)tok*EMBn + k8);
    float4 x1 = *(const float4*)(emb + (size_t)tok*EMBn + k8 + 4);
    ushort4 lo = { f2bf(x0.x), f2bf(x0.y), f2bf(x0.z), f2bf(x0.w) };
    ushort4 hi = { f2bf(x1.x), f2bf(x1.y), f2bf(x1.z), f2bf(x1.w) };
    *(ushort4*)&A_x[mm][k8]     = lo;
    *(ushort4*)&A_x[mm][k8 + 4] = hi;
  }
  __syncthreads();

  int colbase = cgrp*256 + wv*64;
  v4f acc[4];
  #pragma unroll
  for (int ct = 0; ct < 4; ++ct){
    float bz = bpk[d*NG + colbase + ct*16 + r];
    acc[ct] = (v4f){bz, bz, bz, bz};
  }
  #pragma unroll
  for (int kt = 0; kt < 4; ++kt){
    v8s a = *(const v8s*)&A_x[r][kt*32 + q*8];
    #pragma unroll
    for (int ct = 0; ct < 4; ++ct){
      const v8s bfr = *(const v8s*)(UW +
          ((size_t)(d*NG + colbase + ct*16 + r))*NK + 256 + kt*32 + q*8);
      acc[ct] = __builtin_amdgcn_mfma_f32_16x16x32_bf16(a, bfr, acc[ct], 0, 0, 0);
    }
  }
  // C layout: col = lane&15 (within tile), row(token) = q*4 + i
  if (use_fp8){
    unsigned char* xz = (unsigned char*)xz_v;
    #pragma unroll
    for (int ct = 0; ct < 4; ++ct){
      int col = colbase + ct*16 + r;
      #pragma unroll
      for (int i = 0; i < 4; ++i){
        int n = n0 + q*4 + i;
        xz[((size_t)(d*Sn + s)*Bn + (n & 63))*NG + col] = f8e(acc[ct][i]);
      }
    }
  } else {
    unsigned short* xz = (unsigned short*)xz_v;
    #pragma unroll
    for (int ct = 0; ct < 4; ++ct){
      int col = colbase + ct*16 + r;
      #pragma unroll
      for (int i = 0; i < 4; ++i){
        int n = n0 + q*4 + i;
        xz[((size_t)(d*Sn + s)*Bn + (n & 63))*NG + col] = f2bf(acc[ct][i]);
      }
    }
  }
}

// ---------------------------------------------------------------------------
// Persistent bidirectional LSTM, recurrent part only (z = xz + h@U).
// grid = (8 groups, 2 col-halves) = 16 blocks, 512 threads. Per-wave weights
// wf[4][8] = 128 VGPRs (U only; x-projection hoisted to k_xw) -> total
// register demand ~200 < 256 cap: no spill (r3-r5 were spill-BW-bound).
// Cross-block h exchange: self-validating tagged u64s, relaxed agent atomics.
// ---------------------------------------------------------------------------
__global__ __launch_bounds__(512, 2) void k_lstm(
    const unsigned short* __restrict__ UW, const void* __restrict__ xz_v,
    int use_fp8, unsigned short* __restrict__ h_hist, u64t* __restrict__ hbuf)
{
  __shared__ unsigned short A_s[16][264];  // h_prev (256 + pad)
  __shared__ float z_s[16*520];            // zsw() layout

  int g  = blockIdx.x;                     // d*4 + bg
  int cg = blockIdx.y;                     // col half
  int d  = g >> 2, bg = g & 3;
  int tid = threadIdx.x;
  int wv = tid >> 6, lane = tid & 63, q = lane >> 4, r = lane & 15;
  int m  = tid >> 5, g32 = tid & 31;

  u64t* pub = hbuf + (size_t)(g*2 + cg)*2048;
  u64t* sub = hbuf + (size_t)(g*2 + (cg^1))*2048;

  // ---- register-stationary U fragments: slots 0..3 own half, 4..7 partner ----
  v8s wf[4][8];
  #pragma unroll
  for (int ct = 0; ct < 4; ++ct){
    const unsigned short* base =
        UW + ((size_t)(d*NG + cg*512 + wv*64 + ct*16 + r))*NK;
    #pragma unroll
    for (int j = 0; j < 4; ++j)
      wf[ct][j] = *(const v8s*)(base + (cg*4 + j)*32 + q*8);
    #pragma unroll
    for (int j = 0; j < 4; ++j)
      wf[ct][4 + j] = *(const v8s*)(base + ((cg^1)*4 + j)*32 + q*8);
  }

  // ---- xz prefetch for t = 0 (thread (m,g32): 16 cols at cg*512+g32*16) ----
  size_t xz_tstride = (size_t)Bn*NG;
  size_t xz_base = (size_t)(bg*16 + m)*NG + cg*512 + g32*16;
  int t0_act = d ? (Sn - 1) : 0;
  uint4 xza, xzb;
  if (use_fp8){
    xza = *(const uint4*)((const unsigned char*)xz_v +
          ((size_t)d*Sn + t0_act)*xz_tstride + xz_base);
  } else {
    const uint4* p = (const uint4*)((const unsigned short*)xz_v +
          (((size_t)d*Sn + t0_act)*xz_tstride + xz_base));
    xza = p[0]; xzb = p[1];
  }
  float c_[4] = {0.f, 0.f, 0.f, 0.f};
  __syncthreads();

  #pragma unroll 1
  for (int t = 0; t < Sn; ++t){
    int t_act = d ? (Sn - 1 - t) : t;

    v4f acc[4];
    #pragma unroll
    for (int ct = 0; ct < 4; ++ct) acc[ct] = (v4f){0.f,0.f,0.f,0.f};

    if (t > 0){
      // ---- phase 1: own h half (slots 0..3) ----
      #pragma unroll
      for (int j = 0; j < 4; ++j){
        v8s a = *(const v8s*)&A_s[r][cg*128 + j*32 + q*8];
        #pragma unroll
        for (int ct = 0; ct < 4; ++ct)
          acc[ct] = __builtin_amdgcn_mfma_f32_16x16x32_bf16(a, wf[ct][j], acc[ct], 0, 0, 0);
      }
      // ---- poll partner h_{t-1} (tag == t), both slots in parallel ----
      unsigned tgt = (unsigned)t;
      u64t* src = sub + (size_t)((t - 1) & 1)*1024 + (m*32 + g32)*2;
      u64t a0, a1;
      for (;;){
        a0 = __hip_atomic_load(src,     __ATOMIC_RELAXED, __HIP_MEMORY_SCOPE_AGENT);
        a1 = __hip_atomic_load(src + 1, __ATOMIC_RELAXED, __HIP_MEMORY_SCOPE_AGENT);
        if ((unsigned)(a0 & 0xFFFFu) == tgt && (unsigned)(a1 & 0xFFFFu) == tgt) break;
        __builtin_amdgcn_s_sleep(1);
      }
      ushort4 hv = { (unsigned short)(a0 >> 16), (unsigned short)(a0 >> 32),
                     (unsigned short)(a1 >> 16), (unsigned short)(a1 >> 32) };
      *(ushort4*)&A_s[m][(cg^1)*128 + g32*4] = hv;
    }
    __syncthreads();   // B_A

    if (t > 0){
      // ---- phase 2: partner h half (slots 4..7) ----
      #pragma unroll
      for (int j = 0; j < 4; ++j){
        v8s a = *(const v8s*)&A_s[r][(cg^1)*128 + j*32 + q*8];
        #pragma unroll
        for (int ct = 0; ct < 4; ++ct)
          acc[ct] = __builtin_amdgcn_mfma_f32_16x16x32_bf16(a, wf[ct][4 + j], acc[ct], 0, 0, 0);
      }
    }
    #pragma unroll
    for (int ct = 0; ct < 4; ++ct){
      int col = wv*64 + ct*16 + r;
      #pragma unroll
      for (int i = 0; i < 4; ++i)
        z_s[zsw(q*4 + i, col)] = acc[ct][i];
    }
    __syncthreads();   // B_z

    // ---- gates: z = z_s (h@U) + xz (x@W + bias) ----
    unsigned short hsh[4];
    {
      float xv[16];
      if (use_fp8){
        const unsigned char* xp = (const unsigned char*)&xza;
        #pragma unroll
        for (int i = 0; i < 16; ++i) xv[i] = f8d(xp[i]);
      } else {
        const unsigned short* xp = (const unsigned short*)&xza;  // xza,xzb adjacent
        uint4 tmp[2] = { xza, xzb };
        const unsigned short* xq = (const unsigned short*)tmp;
        #pragma unroll
        for (int i = 0; i < 16; ++i) xv[i] = bf2f(xq[i]);
        (void)xp;
      }
      #pragma unroll
      for (int i = 0; i < 4; ++i){
        float4 z4 = *(const float4*)&z_s[zsw(m, g32*16 + i*4)];
        float ii = sigm(z4.x + xv[i*4    ]);
        float ff = sigm(z4.y + xv[i*4 + 1]);
        float gg = tanh_(z4.z + xv[i*4 + 2]);
        float oo = sigm(z4.w + xv[i*4 + 3]);
        c_[i] = ff*c_[i] + ii*gg;
        hsh[i] = f2bf(oo*tanh_(c_[i]));
      }
    }
    // ---- prefetch xz for t+1 (off critical path) ----
    if (t < Sn - 1){
      int tn = d ? (Sn - 2 - t) : (t + 1);
      if (use_fp8){
        xza = *(const uint4*)((const unsigned char*)xz_v +
              ((size_t)d*Sn + tn)*xz_tstride + xz_base);
      } else {
        const uint4* p = (const uint4*)((const unsigned short*)xz_v +
              (((size_t)d*Sn + tn)*xz_tstride + xz_base));
        xza = p[0]; xzb = p[1];
      }
    }
    // ---- publish (tagged, fire-and-forget) ----
    {
      u64t tag = (u64t)(t + 1);
      u64t lo = tag | ((u64t)hsh[0] << 16) | ((u64t)hsh[1] << 32);
      u64t hi = tag | ((u64t)hsh[2] << 16) | ((u64t)hsh[3] << 32);
      u64t* dst = pub + (size_t)(t & 1)*1024 + (m*32 + g32)*2;
      __hip_atomic_store(dst,     lo, __ATOMIC_RELAXED, __HIP_MEMORY_SCOPE_AGENT);
      __hip_atomic_store(dst + 1, hi, __ATOMIC_RELAXED, __HIP_MEMORY_SCOPE_AGENT);
    }
    // ---- own h -> A_s + h_hist ----
    {
      ushort4 hv = { hsh[0], hsh[1], hsh[2], hsh[3] };
      *(ushort4*)&A_s[m][cg*128 + g32*4] = hv;
      u64t hp = (u64t)hsh[0] | ((u64t)hsh[1] << 16) |
                ((u64t)hsh[2] << 32) | ((u64t)hsh[3] << 48);
      *(u64t*)(h_hist + ((size_t)(d*Sn + t_act)*Bn + bg*16 + m)*HIDn
               + cg*128 + g32*4) = hp;
    }
    __syncthreads();   // B_end
  }
}

// ---------------------------------------------------------------------------
__global__ __launch_bounds__(256) void k_logits(
    const unsigned short* __restrict__ h_hist, const float* __restrict__ Wd,
    const float* __restrict__ bd, float* __restrict__ out)
{
  __shared__ float Wd_s[2*HIDn*NTAG];
  __shared__ float bd_s[NTAG];
  for (int i = threadIdx.x; i < 2*HIDn*NTAG; i += 256) Wd_s[i] = Wd[i];
  if (threadIdx.x < NTAG) bd_s[threadIdx.x] = bd[threadIdx.x];
  __syncthreads();

  int n = blockIdx.x*256 + threadIdx.x;
  int b = n >> 9, s = n & 511;
  float acc[NTAG];
  #pragma unroll
  for (int k = 0; k < NTAG; ++k) acc[k] = bd_s[k];

  const uint4* hf = (const uint4*)(h_hist + ((size_t)s*Bn + b)*HIDn);
  const uint4* hb = (const uint4*)(h_hist + ((size_t)(Sn + s)*Bn + b)*HIDn);
  #pragma unroll 4
  for (int ch = 0; ch < HIDn/8; ++ch){
    uint4 vf = hf[ch], vb = hb[ch];
    unsigned int wsv[8] = {vf.x, vf.y, vf.z, vf.w, vb.x, vb.y, vb.z, vb.w};
    #pragma unroll
    for (int half = 0; half < 2; ++half){
      int jbase = half*HIDn + ch*8;
      #pragma unroll
      for (int e = 0; e < 4; ++e){
        unsigned int u = wsv[half*4 + e];
        float hlo = bf2f((unsigned short)(u & 0xFFFF));
        float hhi = bf2f((unsigned short)(u >> 16));
        const float* w0 = &Wd_s[(jbase + e*2    )*NTAG];
        const float* w1 = &Wd_s[(jbase + e*2 + 1)*NTAG];
        #pragma unroll
        for (int k = 0; k < NTAG; ++k) acc[k] += hlo*w0[k] + hhi*w1[k];
      }
    }
  }
  float* o = out + (size_t)n*NTAG;
  #pragma unroll
  for (int k = 0; k < NTAG; ++k) o[k] = acc[k];
}

// ---------------------------------------------------------------------------
__global__ __launch_bounds__(64) void k_crf(
    const float* __restrict__ logits, const int* __restrict__ labels,
    const float* __restrict__ trans, const int* __restrict__ lens_i,
    float* __restrict__ out_ll)
{
  int b = blockIdx.x, lane = threadIdx.x;
  int len = lens_i[b];
  const float* lg = logits + (size_t)b*Sn*NTAG;
  const int* lab = labels + b*Sn;

  float sc = 0.f;
  for (int s = lane; s < Sn; s += 64){
    if (s < len)     sc += lg[s*NTAG + lab[s]];
    if (s < len - 1) sc += trans[lab[s]*NTAG + lab[s+1]];
  }
  for (int off = 32; off; off >>= 1) sc += __shfl_down(sc, off);
  sc = __shfl(sc, 0);

  int j = (lane < NTAG) ? lane : (NTAG - 1);
  float Tj[NTAG];
  #pragma unroll
  for (int i = 0; i < NTAG; ++i) Tj[i] = trans[i*NTAG + j];
  float alpha = lg[j];
  float nxt = lg[NTAG + j];
  for (int t = 1; t < Sn; ++t){
    float cur = nxt;
    if (t < Sn - 1) nxt = lg[(t+1)*NTAG + j];
    float v[NTAG]; float mx;
    v[0] = __shfl(alpha, 0) + Tj[0]; mx = v[0];
    #pragma unroll
    for (int i = 1; i < NTAG; ++i){ v[i] = __shfl(alpha, i) + Tj[i]; mx = fmaxf(mx, v[i]); }
    float ssum = 0.f;
    #pragma unroll
    for (int i = 0; i < NTAG; ++i) ssum += __expf(v[i] - mx);
    float na = mx + __logf(ssum) + cur;
    if (t < len) alpha = na;
  }
  float m2 = __shfl(alpha, 0);
  #pragma unroll
  for (int i = 1; i < NTAG; ++i) m2 = fmaxf(m2, __shfl(alpha, i));
  float s2 = 0.f;
  #pragma unroll
  for (int i = 0; i < NTAG; ++i) s2 += __expf(__shfl(alpha, i) - m2);
  float ln = m2 + __logf(s2);
  if (lane == 0) out_ll[b] = sc - ln;
}

// ---------------------------------------------------------------------------
extern "C" void kernel_launch(void* const* d_in, const int* in_sizes, int n_in,
                              void* d_out, int out_size, void* d_ws, size_t ws_size,
                              hipStream_t stream)
{
  const int*   text   = (const int*)  d_in[0];
  const int*   labels = (const int*)  d_in[1];
  const float* emb    = (const float*)d_in[2];
  const float* W_f    = (const float*)d_in[3];
  const float* U_f    = (const float*)d_in[4];
  const float* b_f    = (const float*)d_in[5];
  const float* W_b    = (const float*)d_in[6];
  const float* U_b    = (const float*)d_in[7];
  const float* b_b    = (const float*)d_in[8];
  const float* W_d    = (const float*)d_in[9];
  const float* b_d    = (const float*)d_in[10];
  const float* trans  = (const float*)d_in[11];
  float* out = (float*)d_out;                  // [logits 294912][lens 64][ll 64]

  // h-exchange scratch in d_out's logits area (256 KiB), overwritten by
  // k_logits afterwards. Tags 0x0000/0xAAAA never match t+1 in [1,512].
  u64t* hbuf = (u64t*)d_out;

  char* w = (char*)d_ws;
  int*            lens_i = (int*)w;                          // 256 B
  float*          bpk    = (float*)(w + 256);                // 8 KiB
  unsigned short* UW     = (unsigned short*)(w + 8448);      // 1.5 MiB
  unsigned short* h_hist = (unsigned short*)(w + 1581312);   // 32 MiB
  void*           xz     = (void*)(w + 35135744);            // 134 MiB bf16 / 67 MiB fp8

  // xz precision: bf16 if workspace allows, else OCP e4m3 (half footprint).
  int use_fp8 = (ws_size < (size_t)35135744 + (size_t)2*Bn*Sn*NG*2) ? 1 : 0;

  hipLaunchKernelGGL(k_conv, dim3(16, 2), dim3(256), 0, stream,
                     W_f, U_f, b_f, W_b, U_b, b_b, UW, bpk);
  hipLaunchKernelGGL(k_lens, dim3(Bn), dim3(64), 0, stream,
                     text, out + Bn*Sn*NTAG, lens_i);
  hipLaunchKernelGGL(k_xw, dim3(Bn*Sn/16, 4, 2), dim3(256), 0, stream,
                     text, emb, UW, bpk, xz, use_fp8);

  void* args[] = { (void*)&UW, (void*)&xz, (void*)&use_fp8,
                   (void*)&h_hist, (void*)&hbuf };
  hipLaunchCooperativeKernel((const void*)k_lstm, dim3(8, 2), dim3(512),
                             args, 0, stream);

  hipLaunchKernelGGL(k_logits, dim3(Bn*Sn/256), dim3(256), 0, stream,
                     h_hist, W_d, b_d, out);
  hipLaunchKernelGGL(k_crf, dim3(Bn), dim3(64), 0, stream,
                     out, labels, trans, lens_i, out + Bn*Sn*NTAG + Bn);
}